// Round 2
// baseline (662.729 us; speedup 1.0000x reference)
//
#include <hip/hip_runtime.h>
#include <cmath>

#define TABLE_SZ 16384
#define NLEV 16
#define BLOCK 1024
#define PPT 2   // points per thread

struct ResArr { float r[NLEV]; };

__global__ __launch_bounds__(BLOCK, 4) void mrhe_kernel(
    const float* __restrict__ x,
    const float* __restrict__ tables,
    float* __restrict__ out,
    ResArr res, int B)
{
    __shared__ float2 tab[TABLE_SZ];   // 128 KiB — one level's table

    const int tid  = threadIdx.x;
    const int base = blockIdx.x * (BLOCK * PPT);

    // ---- load point coords (interleaved for coalescing) ----
    float px[PPT], py[PPT], pz[PPT];
    bool  valid[PPT];
    #pragma unroll
    for (int p = 0; p < PPT; ++p) {
        int idx = base + p * BLOCK + tid;
        valid[p] = idx < B;
        size_t j = valid[p] ? (size_t)idx : 0;
        px[p] = x[3*j+0];
        py[p] = x[3*j+1];
        pz[p] = x[3*j+2];
    }

    // interp weights from UNSCALED position (faithful: w = x - floor(x))
    float wx[PPT], wy[PPT], wz[PPT];
    #pragma unroll
    for (int p = 0; p < PPT; ++p) {
        wx[p] = px[p] - floorf(px[p]);
        wy[p] = py[p] - floorf(py[p]);
        wz[p] = pz[p] - floorf(pz[p]);
    }

    const uint32_t P1 = 2654435761u, P2 = 805459861u;
    const uint32_t m  = TABLE_SZ - 1u;

    float o[PPT][2*NLEV];   // statically indexed only (unrolled loops)

    #pragma unroll
    for (int l = 0; l < NLEV; ++l) {
        // ---- stage level-l table into LDS ----
        __syncthreads();   // protect previous level's readers
        {
            const float4* src4 = (const float4*)(tables + (size_t)l * TABLE_SZ * 2);
            float4* dst4 = (float4*)tab;
            #pragma unroll
            for (int j = 0; j < (TABLE_SZ*2/4)/BLOCK; ++j)   // 8 rounds
                dst4[j*BLOCK + tid] = src4[j*BLOCK + tid];
        }
        __syncthreads();

        const float r = res.r[l];

        #pragma unroll
        for (int p = 0; p < PPT; ++p) {
            // corner weights, product order (x*y)*z, corners v0..v7
            float ax = 1.0f - wx[p], ay = 1.0f - wy[p], az = 1.0f - wz[p];
            float cw0 = (ax*ay)*az;
            float cw1 = (wx[p]*ay)*az;
            float cw2 = (wx[p]*wy[p])*az;
            float cw3 = (ax*wy[p])*az;
            float cw4 = (ax*ay)*wz[p];
            float cw5 = (wx[p]*ay)*wz[p];
            float cw6 = (wx[p]*wy[p])*wz[p];
            float cw7 = (ax*wy[p])*wz[p];

            float sx = r*px[p], sy = r*py[p], sz = r*pz[p];
            // high = ceil (NOT low+1)
            uint32_t lx = (uint32_t)(int32_t)floorf(sx);
            uint32_t hx = (uint32_t)(int32_t)ceilf(sx);
            uint32_t ly = (uint32_t)(int32_t)floorf(sy);
            uint32_t hy = (uint32_t)(int32_t)ceilf(sy);
            uint32_t lz = (uint32_t)(int32_t)floorf(sz);
            uint32_t hz = (uint32_t)(int32_t)ceilf(sz);
            uint32_t yl = P1*ly, yh = P1*hy;
            uint32_t zl = P2*lz, zh = P2*hz;
            uint32_t h0 = (lx ^ yl ^ zl) & m;
            uint32_t h1 = (hx ^ yl ^ zl) & m;
            uint32_t h2 = (hx ^ yh ^ zl) & m;
            uint32_t h3 = (lx ^ yh ^ zl) & m;
            uint32_t h4 = (lx ^ yl ^ zh) & m;
            uint32_t h5 = (hx ^ yl ^ zh) & m;
            uint32_t h6 = (hx ^ yh ^ zh) & m;
            uint32_t h7 = (lx ^ yh ^ zh) & m;

            float2 f0 = tab[h0]; float2 f1 = tab[h1];
            float2 f2 = tab[h2]; float2 f3 = tab[h3];
            float2 f4 = tab[h4]; float2 f5 = tab[h5];
            float2 f6 = tab[h6]; float2 f7 = tab[h7];

            float a0 = f0.x*cw0;  float a1 = f0.y*cw0;
            a0 += f1.x*cw1;       a1 += f1.y*cw1;
            a0 += f2.x*cw2;       a1 += f2.y*cw2;
            a0 += f3.x*cw3;       a1 += f3.y*cw3;
            a0 += f4.x*cw4;       a1 += f4.y*cw4;
            a0 += f5.x*cw5;       a1 += f5.y*cw5;
            a0 += f6.x*cw6;       a1 += f6.y*cw6;
            a0 += f7.x*cw7;       a1 += f7.y*cw7;

            o[p][2*l+0] = a0;
            o[p][2*l+1] = a1;
        }
    }

    // ---- epilogue: full-line 128 B per point, 8x float4 ----
    #pragma unroll
    for (int p = 0; p < PPT; ++p) {
        if (!valid[p]) continue;
        size_t idx = (size_t)(base + p * BLOCK + tid);
        float4* po = (float4*)(out + idx * (2*NLEV));
        #pragma unroll
        for (int j = 0; j < (2*NLEV)/4; ++j) {
            float4 v;
            v.x = o[p][4*j+0]; v.y = o[p][4*j+1];
            v.z = o[p][4*j+2]; v.w = o[p][4*j+3];
            po[j] = v;
        }
    }
}

extern "C" void kernel_launch(void* const* d_in, const int* in_sizes, int n_in,
                              void* d_out, int out_size, void* d_ws, size_t ws_size,
                              hipStream_t stream)
{
    const float* x      = (const float*)d_in[0];
    const float* tables = (const float*)d_in[1];
    float* out = (float*)d_out;
    int B = in_sizes[0] / 3;

    // Replicate the reference's float32 op chain on host libm:
    // b = exp((log(512)-log(16))/15); res_l = floor(16 * b**l)
    ResArr res;
    float bgrow = expf((logf(512.0f) - logf(16.0f)) / 15.0f);
    for (int l = 0; l < NLEV; ++l)
        res.r[l] = floorf(16.0f * powf(bgrow, (float)l));

    int per_block = BLOCK * PPT;
    int grid = (B + per_block - 1) / per_block;
    hipLaunchKernelGGL(mrhe_kernel, dim3(grid), dim3(BLOCK), 0, stream,
                       x, tables, out, res, B);
}

// Round 3
// 443.071 us; speedup vs baseline: 1.4958x; 1.4958x over previous
//
#include <hip/hip_runtime.h>
#include <cmath>

#define TABLE_SZ 16384
#define NLEV 16
#define BLOCK 1024
#define PPT 2          // points per thread
#define HALF_LEV 8     // levels per half-pass

struct ResArr { float r[NLEV]; };

__global__ __launch_bounds__(BLOCK, 2) void mrhe_kernel(
    const float* __restrict__ x,
    const float* __restrict__ tables,
    float* __restrict__ out,
    ResArr res, int B)
{
    __shared__ float2 tab[TABLE_SZ];   // 128 KiB — one level's table

    const int tid  = threadIdx.x;
    const int wid  = tid >> 6;
    const int base = blockIdx.x * (BLOCK * PPT);

    // ---- load point coords (block-interleaved for coalescing) ----
    float px[PPT], py[PPT], pz[PPT];
    bool  valid[PPT];
    #pragma unroll
    for (int p = 0; p < PPT; ++p) {
        int idx = base + p * BLOCK + tid;
        valid[p] = idx < B;
        size_t j = valid[p] ? (size_t)idx : 0;
        px[p] = x[3*j+0];
        py[p] = x[3*j+1];
        pz[p] = x[3*j+2];
    }

    // interp weights from UNSCALED position (faithful: w = x - floor(x))
    // corner weights, product order (x*y)*z, corners v0..v7
    float cw[PPT][8];
    #pragma unroll
    for (int p = 0; p < PPT; ++p) {
        float wx = px[p] - floorf(px[p]);
        float wy = py[p] - floorf(py[p]);
        float wz = pz[p] - floorf(pz[p]);
        float ax = 1.0f - wx, ay = 1.0f - wy, az = 1.0f - wz;
        cw[p][0] = (ax*ay)*az;
        cw[p][1] = (wx*ay)*az;
        cw[p][2] = (wx*wy)*az;
        cw[p][3] = (ax*wy)*az;
        cw[p][4] = (ax*ay)*wz;
        cw[p][5] = (wx*ay)*wz;
        cw[p][6] = (wx*wy)*wz;
        cw[p][7] = (ax*wy)*wz;
    }

    const uint32_t P1 = 2654435761u, P2 = 805459861u;
    const uint32_t m  = TABLE_SZ - 1u;

    #pragma unroll
    for (int half = 0; half < NLEV / HALF_LEV; ++half) {
        float o[PPT][2*HALF_LEV];   // 32 floats live — statically indexed

        #pragma unroll
        for (int hl = 0; hl < HALF_LEV; ++hl) {
            const int l = half * HALF_LEV + hl;

            // ---- stage level-l table into LDS (async, zero VGPR) ----
            __syncthreads();   // protect previous level's readers
            {
                const char* gbase = (const char*)(tables + (size_t)l * TABLE_SZ * 2);
                char* lbase = (char*)tab;
                #pragma unroll
                for (int j = 0; j < (TABLE_SZ * 8) / (BLOCK * 16); ++j) {  // 8 rounds
                    size_t goff = ((size_t)j * BLOCK + tid) * 16;        // per-lane
                    size_t loff = ((size_t)j * BLOCK + wid * 64) * 16;   // wave-uniform
                    __builtin_amdgcn_global_load_lds(
                        (const __attribute__((address_space(1))) uint32_t*)(gbase + goff),
                        (__attribute__((address_space(3))) uint32_t*)(lbase + loff),
                        16, 0, 0);
                }
            }
            __syncthreads();   // implies vmcnt/lgkm drain

            const float r = res.r[l];

            #pragma unroll
            for (int p = 0; p < PPT; ++p) {
                float sx = r*px[p], sy = r*py[p], sz = r*pz[p];
                // high = ceil (NOT low+1)
                uint32_t lx = (uint32_t)(int32_t)floorf(sx);
                uint32_t hx = (uint32_t)(int32_t)ceilf(sx);
                uint32_t ly = (uint32_t)(int32_t)floorf(sy);
                uint32_t hy = (uint32_t)(int32_t)ceilf(sy);
                uint32_t lz = (uint32_t)(int32_t)floorf(sz);
                uint32_t hz = (uint32_t)(int32_t)ceilf(sz);
                uint32_t yl = P1*ly, yh = P1*hy;
                uint32_t zl = P2*lz, zh = P2*hz;
                uint32_t h0 = (lx ^ yl ^ zl) & m;
                uint32_t h1 = (hx ^ yl ^ zl) & m;
                uint32_t h2 = (hx ^ yh ^ zl) & m;
                uint32_t h3 = (lx ^ yh ^ zl) & m;
                uint32_t h4 = (lx ^ yl ^ zh) & m;
                uint32_t h5 = (hx ^ yl ^ zh) & m;
                uint32_t h6 = (hx ^ yh ^ zh) & m;
                uint32_t h7 = (lx ^ yh ^ zh) & m;

                float2 f0 = tab[h0]; float2 f1 = tab[h1];
                float2 f2 = tab[h2]; float2 f3 = tab[h3];
                float2 f4 = tab[h4]; float2 f5 = tab[h5];
                float2 f6 = tab[h6]; float2 f7 = tab[h7];

                float a0 = f0.x*cw[p][0];  float a1 = f0.y*cw[p][0];
                a0 += f1.x*cw[p][1];       a1 += f1.y*cw[p][1];
                a0 += f2.x*cw[p][2];       a1 += f2.y*cw[p][2];
                a0 += f3.x*cw[p][3];       a1 += f3.y*cw[p][3];
                a0 += f4.x*cw[p][4];       a1 += f4.y*cw[p][4];
                a0 += f5.x*cw[p][5];       a1 += f5.y*cw[p][5];
                a0 += f6.x*cw[p][6];       a1 += f6.y*cw[p][6];
                a0 += f7.x*cw[p][7];       a1 += f7.y*cw[p][7];

                o[p][2*hl+0] = a0;
                o[p][2*hl+1] = a1;
            }
        }

        // ---- write this half's 64 contiguous bytes per point ----
        #pragma unroll
        for (int p = 0; p < PPT; ++p) {
            if (!valid[p]) continue;
            size_t idx = (size_t)(base + p * BLOCK + tid);
            float4* po = (float4*)(out + idx * (2*NLEV) + half * (2*HALF_LEV));
            #pragma unroll
            for (int j = 0; j < (2*HALF_LEV)/4; ++j) {
                float4 v;
                v.x = o[p][4*j+0]; v.y = o[p][4*j+1];
                v.z = o[p][4*j+2]; v.w = o[p][4*j+3];
                po[j] = v;
            }
        }
    }
}

extern "C" void kernel_launch(void* const* d_in, const int* in_sizes, int n_in,
                              void* d_out, int out_size, void* d_ws, size_t ws_size,
                              hipStream_t stream)
{
    const float* x      = (const float*)d_in[0];
    const float* tables = (const float*)d_in[1];
    float* out = (float*)d_out;
    int B = in_sizes[0] / 3;

    // Replicate the reference's float32 op chain on host libm:
    // b = exp((log(512)-log(16))/15); res_l = floor(16 * b**l)
    ResArr res;
    float bgrow = expf((logf(512.0f) - logf(16.0f)) / 15.0f);
    for (int l = 0; l < NLEV; ++l)
        res.r[l] = floorf(16.0f * powf(bgrow, (float)l));

    int per_block = BLOCK * PPT;
    int grid = (B + per_block - 1) / per_block;
    hipLaunchKernelGGL(mrhe_kernel, dim3(grid), dim3(BLOCK), 0, stream,
                       x, tables, out, res, B);
}

// Round 4
// 278.616 us; speedup vs baseline: 2.3786x; 1.5903x over previous
//
#include <hip/hip_runtime.h>
#include <cmath>

#define TABLE_SZ 16384
#define NLEV 16
#define BLOCK 512
#define PPT 8          // points per thread -> 4096 points/block, grid = 256
#define QLEV 2         // levels per pass -> 8 passes, one float4 store each

struct ResArr { float r[NLEV]; };

__global__ __launch_bounds__(BLOCK) void mrhe_kernel(
    const float* __restrict__ x,
    const float* __restrict__ tables,
    float* __restrict__ out,
    ResArr res, int B)
{
    __shared__ float2 tab[TABLE_SZ];   // 128 KiB — one level's table

    const int tid  = threadIdx.x;
    const int wid  = tid >> 6;
    const int base = blockIdx.x * (BLOCK * PPT);

    // ---- load point coords (block-interleaved for coalescing) ----
    // x in [0,1): interp weight w = x - floor(x) == x exactly (reference notes
    // this), so px/py/pz double as the trilinear weights. No weight arrays.
    float px[PPT], py[PPT], pz[PPT];
    #pragma unroll
    for (int p = 0; p < PPT; ++p) {
        int idx = base + p * BLOCK + tid;
        size_t j = (idx < B) ? (size_t)idx : 0;
        px[p] = x[3*j+0];
        py[p] = x[3*j+1];
        pz[p] = x[3*j+2];
    }

    const uint32_t P1 = 2654435761u, P2 = 805459861u;
    const uint32_t m  = TABLE_SZ - 1u;

    for (int pass = 0; pass < NLEV / QLEV; ++pass) {   // runtime loop (small I$)
        float o[PPT][2*QLEV];                          // 32 floats, static idx only

        #pragma unroll
        for (int q = 0; q < QLEV; ++q) {
            const int l = pass * QLEV + q;

            // ---- stage level-l table into LDS (async, zero staging VGPRs) ----
            __syncthreads();   // protect previous level's readers
            {
                const char* gbase = (const char*)tables + (size_t)l * (TABLE_SZ * 8);
                #pragma unroll
                for (int j = 0; j < (TABLE_SZ * 8) / (BLOCK * 16); ++j) {  // 16 rounds
                    uint32_t goff = (uint32_t)(j * (BLOCK * 16) + tid * 16);   // per-lane
                    uint32_t loff = (uint32_t)(j * (BLOCK * 16) + wid * 1024); // wave-uniform
                    __builtin_amdgcn_global_load_lds(
                        (const __attribute__((address_space(1))) uint32_t*)(gbase + goff),
                        (__attribute__((address_space(3))) uint32_t*)((char*)tab + loff),
                        16, 0, 0);
                }
            }
            __syncthreads();   // compiler drains vmcnt before s_barrier

            const float r = res.r[l];

            #pragma unroll
            for (int p = 0; p < PPT; ++p) {
                // corner weights, product order (x*y)*z, corners v0..v7
                float ax = 1.0f - px[p], ay = 1.0f - py[p], az = 1.0f - pz[p];
                float cw0 = (ax*ay)*az;
                float cw1 = (px[p]*ay)*az;
                float cw2 = (px[p]*py[p])*az;
                float cw3 = (ax*py[p])*az;
                float cw4 = (ax*ay)*pz[p];
                float cw5 = (px[p]*ay)*pz[p];
                float cw6 = (px[p]*py[p])*pz[p];
                float cw7 = (ax*py[p])*pz[p];

                float sx = r*px[p], sy = r*py[p], sz = r*pz[p];
                // high = ceil (NOT low+1)
                uint32_t lx = (uint32_t)(int32_t)floorf(sx);
                uint32_t hx = (uint32_t)(int32_t)ceilf(sx);
                uint32_t ly = (uint32_t)(int32_t)floorf(sy);
                uint32_t hy = (uint32_t)(int32_t)ceilf(sy);
                uint32_t lz = (uint32_t)(int32_t)floorf(sz);
                uint32_t hz = (uint32_t)(int32_t)ceilf(sz);
                uint32_t yl = P1*ly, yh = P1*hy;
                uint32_t zl = P2*lz, zh = P2*hz;
                uint32_t h0 = (lx ^ yl ^ zl) & m;
                uint32_t h1 = (hx ^ yl ^ zl) & m;
                uint32_t h2 = (hx ^ yh ^ zl) & m;
                uint32_t h3 = (lx ^ yh ^ zl) & m;
                uint32_t h4 = (lx ^ yl ^ zh) & m;
                uint32_t h5 = (hx ^ yl ^ zh) & m;
                uint32_t h6 = (hx ^ yh ^ zh) & m;
                uint32_t h7 = (lx ^ yh ^ zh) & m;

                float2 f0 = tab[h0]; float2 f1 = tab[h1];
                float2 f2 = tab[h2]; float2 f3 = tab[h3];
                float2 f4 = tab[h4]; float2 f5 = tab[h5];
                float2 f6 = tab[h6]; float2 f7 = tab[h7];

                float a0 = f0.x*cw0;  float a1 = f0.y*cw0;
                a0 += f1.x*cw1;       a1 += f1.y*cw1;
                a0 += f2.x*cw2;       a1 += f2.y*cw2;
                a0 += f3.x*cw3;       a1 += f3.y*cw3;
                a0 += f4.x*cw4;       a1 += f4.y*cw4;
                a0 += f5.x*cw5;       a1 += f5.y*cw5;
                a0 += f6.x*cw6;       a1 += f6.y*cw6;
                a0 += f7.x*cw7;       a1 += f7.y*cw7;

                o[p][2*q+0] = a0;
                o[p][2*q+1] = a1;
            }
        }

        // ---- one float4 store per point for this pass ----
        #pragma unroll
        for (int p = 0; p < PPT; ++p) {
            int idx = base + p * BLOCK + tid;
            if (idx < B) {
                float4 v;
                v.x = o[p][0]; v.y = o[p][1]; v.z = o[p][2]; v.w = o[p][3];
                *(float4*)(out + (size_t)idx * (2*NLEV) + pass * (2*QLEV)) = v;
            }
        }
    }
}

extern "C" void kernel_launch(void* const* d_in, const int* in_sizes, int n_in,
                              void* d_out, int out_size, void* d_ws, size_t ws_size,
                              hipStream_t stream)
{
    const float* x      = (const float*)d_in[0];
    const float* tables = (const float*)d_in[1];
    float* out = (float*)d_out;
    int B = in_sizes[0] / 3;

    // Replicate the reference's float32 op chain on host libm:
    // b = exp((log(512)-log(16))/15); res_l = floor(16 * b**l)
    ResArr res;
    float bgrow = expf((logf(512.0f) - logf(16.0f)) / 15.0f);
    for (int l = 0; l < NLEV; ++l)
        res.r[l] = floorf(16.0f * powf(bgrow, (float)l));

    int per_block = BLOCK * PPT;
    int grid = (B + per_block - 1) / per_block;
    hipLaunchKernelGGL(mrhe_kernel, dim3(grid), dim3(BLOCK), 0, stream,
                       x, tables, out, res, B);
}